// Round 1
// baseline (152.006 us; speedup 1.0000x reference)
//
#include <hip/hip_runtime.h>

// Problem constants (fixed by reference setup_inputs)
#define BATCH 8
#define NPTS  4096
#define MPTS  4096
#define KDIM  64
#define TILE  128
#define LSTR  72   // LDS row stride in shorts: 64 data + 8 pad = 144 B (16B-aligned, 2-way bank alias only)

typedef float          f32x4 __attribute__((ext_vector_type(4)));
typedef short          s16x8 __attribute__((ext_vector_type(8)));
typedef unsigned short u16x4 __attribute__((ext_vector_type(4)));

__device__ __forceinline__ unsigned short f2bf(float f) {
  // round-to-nearest-even fp32 -> bf16 (inputs are finite, no NaN handling needed)
  unsigned int u = __float_as_uint(f);
  u += 0x7FFFu + ((u >> 16) & 1u);
  return (unsigned short)(u >> 16);
}

// One wave per row: ||x||^2 over K=64 (exactly one float per lane), exact fp32.
__global__ void sqnorm_kernel(const float* __restrict__ x, float* __restrict__ out) {
  int wave = (int)((blockIdx.x * blockDim.x + threadIdx.x) >> 6);
  int lane = threadIdx.x & 63;
  float v = x[(size_t)wave * KDIM + lane];
  float s = v * v;
  #pragma unroll
  for (int m = 32; m >= 1; m >>= 1) s += __shfl_xor(s, m, 64);
  if (lane == 0) out[wave] = s;
}

// Main tile kernel: per block, one 128x128 tile of the distance matrix for batch b.
// sq = x2[n] + y2[m] - 2*<x_n, y_m>; min-reduce sq along both axes (sqrt deferred).
__global__ __launch_bounds__(256)
void chamfer_tile_kernel(const float* __restrict__ X, const float* __restrict__ Y,
                         const float* __restrict__ x2, const float* __restrict__ y2,
                         unsigned int* __restrict__ rowmin_g,   // [B*N] min over m of sq
                         unsigned int* __restrict__ colmin_g) { // [B*M] min over n of sq
  __shared__ unsigned short Xs[TILE * LSTR];
  __shared__ unsigned short Ys[TILE * LSTR];
  __shared__ unsigned int l_rowmin[TILE];
  __shared__ unsigned int l_colmin[TILE];

  const int b  = blockIdx.z;
  const int n0 = blockIdx.y * TILE;
  const int m0 = blockIdx.x * TILE;
  const int t  = threadIdx.x;

  if (t < TILE) l_rowmin[t] = 0x7F7F7F7Fu;
  else          l_colmin[t - TILE] = 0x7F7F7F7Fu;

  const float* Xb = X + (size_t)b * NPTS * KDIM;
  const float* Yb = Y + (size_t)b * MPTS * KDIM;

  // Stage both tiles to LDS as bf16. 256 threads: thread t covers rows (t>>2) and
  // (t>>2)+64, 16 floats each (seg = t&3). Coalesced: 4 consecutive lanes = one row.
  {
    const int r   = t >> 2;
    const int seg = t & 3;
    #pragma unroll
    for (int half = 0; half < 2; ++half) {
      const int row = r + half * 64;
      const f32x4* srcx = (const f32x4*)(Xb + (size_t)(n0 + row) * KDIM + seg * 16);
      const f32x4* srcy = (const f32x4*)(Yb + (size_t)(m0 + row) * KDIM + seg * 16);
      #pragma unroll
      for (int q = 0; q < 4; ++q) {
        f32x4 vx = srcx[q];
        f32x4 vy = srcy[q];
        u16x4 hx, hy;
        hx[0] = f2bf(vx[0]); hx[1] = f2bf(vx[1]); hx[2] = f2bf(vx[2]); hx[3] = f2bf(vx[3]);
        hy[0] = f2bf(vy[0]); hy[1] = f2bf(vy[1]); hy[2] = f2bf(vy[2]); hy[3] = f2bf(vy[3]);
        *(u16x4*)&Xs[row * LSTR + seg * 16 + q * 4] = hx;
        *(u16x4*)&Ys[row * LSTR + seg * 16 + q * 4] = hy;
      }
    }
  }
  __syncthreads();

  // 4 waves in 2x2; each wave computes a 64x64 subtile as 4x4 MFMA 16x16 tiles.
  const int wave = t >> 6;
  const int lane = t & 63;
  const int wr = (wave >> 1) * 64;   // wave's row offset in tile
  const int wc = (wave & 1) * 64;    // wave's col offset in tile
  const int c  = lane & 15;
  const int q  = lane >> 4;

  f32x4 acc[4][4] = {};

  #pragma unroll
  for (int ks = 0; ks < 2; ++ks) {   // K=64 in two 32-steps
    s16x8 a[4], bb[4];
    #pragma unroll
    for (int i = 0; i < 4; ++i)
      a[i] = *(const s16x8*)&Xs[(wr + i * 16 + c) * LSTR + ks * 32 + q * 8];
    #pragma unroll
    for (int j = 0; j < 4; ++j)
      bb[j] = *(const s16x8*)&Ys[(wc + j * 16 + c) * LSTR + ks * 32 + q * 8];
    #pragma unroll
    for (int i = 0; i < 4; ++i)
      #pragma unroll
      for (int j = 0; j < 4; ++j)
        acc[i][j] = __builtin_amdgcn_mfma_f32_16x16x32_bf16(a[i], bb[j], acc[i][j], 0, 0, 0);
  }

  // Epilogue. C/D layout: col = j*16 + (lane&15), row = i*16 + (lane>>4)*4 + reg.
  const float* x2b = x2 + b * NPTS + n0;
  const float* y2b = y2 + b * MPTS + m0;
  float x2r[4][4];
  #pragma unroll
  for (int i = 0; i < 4; ++i)
    #pragma unroll
    for (int r = 0; r < 4; ++r)
      x2r[i][r] = x2b[wr + i * 16 + q * 4 + r];
  float y2c[4];
  #pragma unroll
  for (int j = 0; j < 4; ++j) y2c[j] = y2b[wc + j * 16 + c];

  const float FINF = 3.0e38f;
  float rm[4][4];  // per-lane min over j, for each (i, reg)
  float cm[4];     // per-lane min over (i, reg), for each j
  #pragma unroll
  for (int j = 0; j < 4; ++j) cm[j] = FINF;
  #pragma unroll
  for (int i = 0; i < 4; ++i) {
    #pragma unroll
    for (int r = 0; r < 4; ++r) {
      float best = FINF;
      #pragma unroll
      for (int j = 0; j < 4; ++j) {
        float sq = fmaf(-2.0f, acc[i][j][r], x2r[i][r] + y2c[j]);
        best = fminf(best, sq);
        cm[j] = fminf(cm[j], sq);
      }
      rm[i][r] = best;
    }
  }

  // Row-min: reduce across the 16 lanes sharing a quad (xor 1,2,4,8).
  #pragma unroll
  for (int msk = 1; msk <= 8; msk <<= 1)
    #pragma unroll
    for (int i = 0; i < 4; ++i)
      #pragma unroll
      for (int r = 0; r < 4; ++r)
        rm[i][r] = fminf(rm[i][r], __shfl_xor(rm[i][r], msk, 64));
  {
    // lane c of quad q owns row i*16 + q*4 + r with i = c>>2, r = c&3
    int i = c >> 2, r = c & 3;
    float v = fmaxf(rm[i][r], 0.0f);  // clamp so uint ordering == float ordering
    atomicMin(&l_rowmin[wr + i * 16 + q * 4 + r], __float_as_uint(v));
  }

  // Col-min: reduce across quads (xor 16, 32).
  #pragma unroll
  for (int msk = 16; msk <= 32; msk <<= 1)
    #pragma unroll
    for (int j = 0; j < 4; ++j)
      cm[j] = fminf(cm[j], __shfl_xor(cm[j], msk, 64));
  {
    int j = q;  // quad q owns col block j == q
    float v = fmaxf(cm[j], 0.0f);
    atomicMin(&l_colmin[wc + j * 16 + c], __float_as_uint(v));
  }

  __syncthreads();
  if (t < TILE) atomicMin(&rowmin_g[b * NPTS + n0 + t], l_rowmin[t]);
  else          atomicMin(&colmin_g[b * MPTS + m0 + (t - TILE)], l_colmin[t - TILE]);
}

// Stage 1: 64 blocks x 256 threads, one uint4 per thread over the 65536 mins.
__global__ void reduce1_kernel(const unsigned int* __restrict__ mins,
                               float* __restrict__ partials) {
  int idx = blockIdx.x * blockDim.x + threadIdx.x;
  uint4 v = ((const uint4*)mins)[idx];
  float s = sqrtf(__uint_as_float(v.x)) + sqrtf(__uint_as_float(v.y)) +
            sqrtf(__uint_as_float(v.z)) + sqrtf(__uint_as_float(v.w));
  #pragma unroll
  for (int m = 32; m >= 1; m >>= 1) s += __shfl_xor(s, m, 64);
  __shared__ float wsum[4];
  if ((threadIdx.x & 63) == 0) wsum[threadIdx.x >> 6] = s;
  __syncthreads();
  if (threadIdx.x == 0) partials[blockIdx.x] = wsum[0] + wsum[1] + wsum[2] + wsum[3];
}

// Stage 2: single wave sums the 64 partials.
__global__ void reduce2_kernel(const float* __restrict__ partials, float* __restrict__ out) {
  float s = partials[threadIdx.x];
  #pragma unroll
  for (int m = 32; m >= 1; m >>= 1) s += __shfl_xor(s, m, 64);
  if (threadIdx.x == 0) out[0] = s * (1.0f / (float)(BATCH * NPTS));
}

extern "C" void kernel_launch(void* const* d_in, const int* in_sizes, int n_in,
                              void* d_out, int out_size, void* d_ws, size_t ws_size,
                              hipStream_t stream) {
  const float* X = (const float*)d_in[0];  // [B, N, K] fp32
  const float* Y = (const float*)d_in[1];  // [B, M, K] fp32
  float* out = (float*)d_out;

  // Workspace layout (floats): mins[65536] | x2[32768] | y2[32768] | partials[64]
  unsigned int* mins = (unsigned int*)d_ws;
  float* x2 = (float*)d_ws + 65536;
  float* y2 = x2 + BATCH * NPTS;
  float* partials = y2 + BATCH * MPTS;

  // Init min buffers to 0x7F7F7F7F (~3.39e38, > any sq) — positive-float uint ordering.
  hipMemsetAsync(mins, 0x7F, (size_t)(BATCH * NPTS + BATCH * MPTS) * sizeof(unsigned int), stream);

  // Exact fp32 squared norms, one wave per row (32768 rows each).
  sqnorm_kernel<<<dim3(BATCH * NPTS / 4), dim3(256), 0, stream>>>(X, x2);
  sqnorm_kernel<<<dim3(BATCH * MPTS / 4), dim3(256), 0, stream>>>(Y, y2);

  // Main fused distance+min kernel: 32x32 tiles x 8 batches = 8192 blocks.
  chamfer_tile_kernel<<<dim3(MPTS / TILE, NPTS / TILE, BATCH), dim3(256), 0, stream>>>(
      X, Y, x2, y2, mins, mins + BATCH * NPTS);

  // Final sqrt + mean.
  reduce1_kernel<<<dim3(64), dim3(256), 0, stream>>>(mins, partials);
  reduce2_kernel<<<dim3(1), dim3(64), 0, stream>>>(partials, out);
}

// Round 2
// 128.335 us; speedup vs baseline: 1.1844x; 1.1844x over previous
//
#include <hip/hip_runtime.h>

// Problem constants (fixed by reference setup_inputs)
#define BATCH 8
#define NPTS  4096   // N == M == 4096
#define KD    64
#define FINF  3.0e38f

typedef float f32x4 __attribute__((ext_vector_type(4)));
typedef float f32x2 __attribute__((ext_vector_type(2)));
typedef short s16x8 __attribute__((ext_vector_type(8)));

__device__ __forceinline__ unsigned int f2bf(float f) {
  // round-to-nearest-even fp32 -> bf16 (inputs finite)
  unsigned int u = __float_as_uint(f);
  u += 0x7FFFu + ((u >> 16) & 1u);
  return u >> 16;
}

__device__ __forceinline__ void stage16(const void* g, void* l) {
  // async global->LDS, 16B/lane; LDS dst = wave-uniform base + lane*16
  __builtin_amdgcn_global_load_lds((const __attribute__((address_space(1))) void*)g,
                                   (__attribute__((address_space(3))) void*)l, 16, 0, 0);
}

// ---------------------------------------------------------------------------
// Prepass: convert X,Y (fp32 [32768][64]) to bf16 packed (uint [32768][32])
// and compute exact fp32 squared norms. 32 threads per row, 2 floats/thread.
__global__ __launch_bounds__(256)
void prep_kernel(const float* __restrict__ X, const float* __restrict__ Y,
                 unsigned int* __restrict__ Xbf, unsigned int* __restrict__ Ybf,
                 float* __restrict__ x2, float* __restrict__ y2) {
  int gid = blockIdx.x * 256 + threadIdx.x;
  int row = gid >> 5;
  int ki  = gid & 31;
  bool isX = row < BATCH * NPTS;
  int r2 = row & (BATCH * NPTS - 1);
  const float* src = isX ? X : Y;
  f32x2 v = *(const f32x2*)(src + (size_t)r2 * KD + ki * 2);
  float s = v[0] * v[0] + v[1] * v[1];
  #pragma unroll
  for (int m = 16; m >= 1; m >>= 1) s += __shfl_xor(s, m, 64);  // stays in 32-lane half
  unsigned int packed = (f2bf(v[1]) << 16) | f2bf(v[0]);
  (isX ? Xbf : Ybf)[r2 * 32 + ki] = packed;
  if (ki == 0) (isX ? x2 : y2)[r2] = s;
}

// ---------------------------------------------------------------------------
// Main: block = (mhalf, ntile, b). 128 rows x 2048 cols walk (16 m-tiles).
// X fragments live in registers across the walk; Y double-buffered in LDS via
// global_load_lds with XOR-swizzled layout (16B chunk index ^ (row&7)).
// Waves = 4 column strips of 32 cols: Y read once, row-mins in registers.
__global__ __launch_bounds__(256, 2)
void chamfer_main(const unsigned short* __restrict__ Xbf,
                  const unsigned short* __restrict__ Ybf,
                  const float* __restrict__ x2g, const float* __restrict__ y2g,
                  float* __restrict__ rowpart,   // [2][B*N] min over mhalf's cols (sq, no sqrt)
                  float* __restrict__ colpart) { // [32][B*M] min over ntile's rows
  __shared__ __align__(16) unsigned short Xs[128 * 64];      // 16 KB
  __shared__ __align__(16) unsigned short Ys[2][128 * 64];   // 32 KB
  __shared__ float l_red[4 * 128];                           // 2 KB

  const int mhalf = blockIdx.x, ntile = blockIdx.y, b = blockIdx.z;
  const int n0 = ntile * 128;
  const int mbase = mhalf * 2048;
  const int t = threadIdx.x, w = t >> 6, lane = t & 63, c = lane & 15, q = lane >> 4;

  // staging source offset within a 1KB (8-row) block: row=lane>>3, chunk=(lane&7)^(lane>>3)
  const int l8 = lane >> 3;
  const int lane_off = l8 * 128 + (((lane & 7) ^ l8) << 4);

  const char* Xg  = (const char*)(Xbf + (size_t)(b * NPTS + n0) * KD);
  const char* Yg0 = (const char*)(Ybf + (size_t)(b * NPTS + mbase) * KD);

  // Prologue: stage X tile + Y tile 0 (4 x 1KB per wave each)
  #pragma unroll
  for (int k = 0; k < 4; ++k) {
    int blockoff = (k * 32 + w * 8) * 128;
    int ldsoff   = (k * 256 + w * 64) * 16;
    stage16(Xg  + blockoff + lane_off, (char*)Xs    + ldsoff);
    stage16(Yg0 + blockoff + lane_off, (char*)Ys[0] + ldsoff);
  }

  // x2 fragment (rows i*16 + q*4 + r), fp32, L2-hot
  f32x4 x2r[8];
  const float* x2b = x2g + b * NPTS + n0;
  #pragma unroll
  for (int i = 0; i < 8; ++i) x2r[i] = *(const f32x4*)(x2b + i * 16 + q * 4);

  __syncthreads();  // drains the global_load_lds (vmcnt 0 at barrier)

  // X fragments -> registers (swizzled ds_read_b128, conflict-free)
  const int cx = c & 7;
  s16x8 xf[8][2];
  #pragma unroll
  for (int i = 0; i < 8; ++i)
    #pragma unroll
    for (int ks = 0; ks < 2; ++ks)
      xf[i][ks] = *(const s16x8*)&Xs[(i * 16 + c) * 64 + ((((ks << 2) + q) ^ cx) << 3)];

  float rm[8][4];
  #pragma unroll
  for (int i = 0; i < 8; ++i)
    #pragma unroll
    for (int r = 0; r < 4; ++r) rm[i][r] = FINF;

  const float* y2b = y2g + b * NPTS + mbase;
  float* colrow = colpart + (size_t)(ntile * 8 + b) * NPTS + mbase;
  const f32x4 zacc = {0.f, 0.f, 0.f, 0.f};

  #pragma unroll 2
  for (int tt = 0; tt < 16; ++tt) {
    unsigned short* cur = Ys[tt & 1];
    unsigned short* nb  = Ys[(tt + 1) & 1];
    if (tt < 15) {  // async-prefetch next Y tile
      const char* Ygt = Yg0 + (size_t)(tt + 1) * 128 * 128;
      #pragma unroll
      for (int k = 0; k < 4; ++k)
        stage16(Ygt + (k * 32 + w * 8) * 128 + lane_off,
                (char*)nb + (k * 256 + w * 64) * 16);
    }
    // y2 for this wave's two 16-col groups (issue early to hide latency)
    float y2c0 = y2b[tt * 128 + w * 32 + c];
    float y2c1 = y2b[tt * 128 + w * 32 + 16 + c];

    s16x8 yf[2][2];
    #pragma unroll
    for (int j = 0; j < 2; ++j)
      #pragma unroll
      for (int ks = 0; ks < 2; ++ks)
        yf[j][ks] = *(const s16x8*)&cur[(w * 32 + j * 16 + c) * 64 +
                                        ((((ks << 2) + q) ^ cx) << 3)];

    f32x4 acc[8][2];
    #pragma unroll
    for (int i = 0; i < 8; ++i)
      #pragma unroll
      for (int j = 0; j < 2; ++j) {
        f32x4 a0 = __builtin_amdgcn_mfma_f32_16x16x32_bf16(xf[i][0], yf[j][0], zacc, 0, 0, 0);
        acc[i][j] = __builtin_amdgcn_mfma_f32_16x16x32_bf16(xf[i][1], yf[j][1], a0, 0, 0, 0);
      }

    // Epilogue: rm' = min(y2 - 2xy) (x2 added at end); cm' = min(x2 - 2xy) (+y2 at store)
    float cm0 = FINF, cm1 = FINF;
    #pragma unroll
    for (int i = 0; i < 8; ++i)
      #pragma unroll
      for (int r = 0; r < 4; ++r) {
        float v0 = acc[i][0][r], v1 = acc[i][1][r];
        rm[i][r] = fminf(rm[i][r], fminf(fmaf(-2.f, v0, y2c0), fmaf(-2.f, v1, y2c1)));
        cm0 = fminf(cm0, fmaf(-2.f, v0, x2r[i][r]));
        cm1 = fminf(cm1, fmaf(-2.f, v1, x2r[i][r]));
      }
    // col-min: reduce over the 4 q-groups (rows), then store (cols wave-private)
    cm0 = fminf(cm0, __shfl_xor(cm0, 16, 64));
    cm0 = fminf(cm0, __shfl_xor(cm0, 32, 64));
    cm1 = fminf(cm1, __shfl_xor(cm1, 16, 64));
    cm1 = fminf(cm1, __shfl_xor(cm1, 32, 64));
    if (q == 0)      colrow[tt * 128 + w * 32 + c]      = cm0 + y2c0;
    else if (q == 1) colrow[tt * 128 + w * 32 + 16 + c] = cm1 + y2c1;

    __syncthreads();  // buffer swap barrier (also drains prefetch vmcnt)
  }

  // Row-min epilogue (once per block): reduce over c within q-group...
  #pragma unroll
  for (int msk = 1; msk <= 8; msk <<= 1)
    #pragma unroll
    for (int i = 0; i < 8; ++i)
      #pragma unroll
      for (int r = 0; r < 4; ++r)
        rm[i][r] = fminf(rm[i][r], __shfl_xor(rm[i][r], msk, 64));
  // ...then across the 4 waves via LDS. Lane c owns (i=c>>1, r=(c&1)*2+{0,1}).
  {
    int ii = c >> 1, rb = (c & 1) * 2;
    l_red[w * 128 + ii * 16 + q * 4 + rb]     = rm[ii][rb];
    l_red[w * 128 + ii * 16 + q * 4 + rb + 1] = rm[ii][rb + 1];
  }
  __syncthreads();
  if (t < 128) {
    float v = fminf(fminf(l_red[t], l_red[128 + t]),
                    fminf(l_red[256 + t], l_red[384 + t]));
    rowpart[mhalf * (BATCH * NPTS) + b * NPTS + n0 + t] = v + x2b[t];
  }
}

// ---------------------------------------------------------------------------
// Final: min over partials, sqrt, mean. 128 blocks x 256 = 32768 threads,
// thread i handles row i (min of 2) and col i (min of 32).
__global__ __launch_bounds__(256)
void reduce_kernel(const float* __restrict__ rowpart, const float* __restrict__ colpart,
                   float* __restrict__ out) {
  int i = blockIdx.x * 256 + threadIdx.x;
  const int TOT = BATCH * NPTS;
  float rv = fminf(rowpart[i], rowpart[TOT + i]);
  float s = sqrtf(fmaxf(rv, 0.f));
  float cv = FINF;
  #pragma unroll
  for (int nt = 0; nt < 32; ++nt) cv = fminf(cv, colpart[nt * TOT + i]);
  s += sqrtf(fmaxf(cv, 0.f));
  #pragma unroll
  for (int m = 32; m >= 1; m >>= 1) s += __shfl_xor(s, m, 64);
  __shared__ float wsum[4];
  if ((threadIdx.x & 63) == 0) wsum[threadIdx.x >> 6] = s;
  __syncthreads();
  if (threadIdx.x == 0)
    atomicAdd(out, (wsum[0] + wsum[1] + wsum[2] + wsum[3]) * (1.0f / (float)TOT));
}

// ---------------------------------------------------------------------------
extern "C" void kernel_launch(void* const* d_in, const int* in_sizes, int n_in,
                              void* d_out, int out_size, void* d_ws, size_t ws_size,
                              hipStream_t stream) {
  const float* X = (const float*)d_in[0];  // [B, N, 64] fp32
  const float* Y = (const float*)d_in[1];  // [B, M, 64] fp32
  float* out = (float*)d_out;

  // Workspace layout (bytes):
  //   Xbf 4MB | Ybf 4MB | x2 128KB | y2 128KB | rowpart 256KB | colpart 4MB
  char* ws = (char*)d_ws;
  unsigned int* Xbf = (unsigned int*)ws;                       // packed bf16 pairs
  unsigned int* Ybf = (unsigned int*)(ws + (4u << 20));
  float* x2 = (float*)(ws + (8u << 20));
  float* y2 = (float*)(ws + (8u << 20) + (128u << 10));
  float* rowpart = (float*)(ws + (8u << 20) + (256u << 10));
  float* colpart = (float*)(ws + (8u << 20) + (512u << 10));

  hipMemsetAsync(out, 0, sizeof(float), stream);

  // Prepass: both inputs, 32 threads/row.
  prep_kernel<<<dim3(2 * BATCH * NPTS * 32 / 256), dim3(256), 0, stream>>>(
      X, Y, Xbf, Ybf, x2, y2);

  // Main: (mhalf=2, ntile=32, b=8) = 512 blocks = 2/CU.
  chamfer_main<<<dim3(2, 32, 8), dim3(256), 0, stream>>>(
      (const unsigned short*)Xbf, (const unsigned short*)Ybf, x2, y2, rowpart, colpart);

  // Final min/sqrt/mean.
  reduce_kernel<<<dim3(BATCH * NPTS / 256), dim3(256), 0, stream>>>(rowpart, colpart, out);
}